// Round 11
// baseline (156.256 us; speedup 1.0000x reference)
//
#include <hip/hip_runtime.h>
#include <hip/hip_bf16.h>
#include <math.h>

#define CDIM 512
#define NROW 8192
#define BM 256
#define BN 256
#define BK 64
#define NT 8               // K tiles: 512/64
#define NCB 32             // column blocks (8192/256)
#define TEMP_INV 10.0f

typedef unsigned short u16;
typedef u16  u16x8 __attribute__((ext_vector_type(8)));
typedef __bf16 bf16x8 __attribute__((ext_vector_type(8)));
typedef float  f32x4 __attribute__((ext_vector_type(4)));

static __device__ __forceinline__ float bf2f(u16 u) {
    return __uint_as_float(((unsigned)u) << 16);
}
static __device__ __forceinline__ u16 f2bf(float f) {
    unsigned u = __float_as_uint(f);
    return (u16)((u + 0x7FFFu + ((u >> 16) & 1u)) >> 16);  // RNE
}

static __device__ __forceinline__ void gload_lds16(const u16* g, char* l) {
    __builtin_amdgcn_global_load_lds(
        (const __attribute__((address_space(1))) void*)g,
        (__attribute__((address_space(3))) void*)l, 16, 0, 0);
}

// ---------------------------------------------------------------------------
// Kernel 1: row-normalize (fp32 math) -> bf16 (RNE). One wave per row.
// ---------------------------------------------------------------------------
__global__ __launch_bounds__(256) void norm_split_kernel(
    const float* __restrict__ x, const float* __restrict__ q,
    u16* __restrict__ xh, u16* __restrict__ qh, int n)
{
    int wave = blockIdx.x * 4 + (threadIdx.x >> 6);
    int lane = threadIdx.x & 63;
    const float* src; u16* dh; int row;
    if (wave < n) { src = x; dh = xh; row = wave; }
    else          { src = q; dh = qh; row = wave - n; }

    const float4* p = reinterpret_cast<const float4*>(src + (size_t)row * CDIM);
    float4 a = p[lane * 2];
    float4 b = p[lane * 2 + 1];
    float v[8] = {a.x, a.y, a.z, a.w, b.x, b.y, b.z, b.w};
    float ss = 0.f;
#pragma unroll
    for (int j = 0; j < 8; ++j) ss += v[j] * v[j];
#pragma unroll
    for (int off = 32; off; off >>= 1) ss += __shfl_xor(ss, off);
    float scale = 1.0f / fmaxf(sqrtf(ss), 1e-12f);

    u16 h[8] __attribute__((aligned(16)));
#pragma unroll
    for (int j = 0; j < 8; ++j) h[j] = f2bf(v[j] * scale);
    *(u16x8*)&dh[(size_t)row * CDIM + lane * 8] = *(u16x8*)h;
}

// ---------------------------------------------------------------------------
// Kernel 2: 256x256 bf16 GEMM (K=512), BK=64, 512 thr = 8 waves (2wm x 4wn),
// wave tile 128x64 (acc[8][4] = 128 AGPR). 2 x 64KB LDS, CLEAN buffer
// alternation: kt reads buf[kt&1], stages kt+1 into buf[(kt+1)&1].
// 4 phases per K-tile: {vmcnt(N); ds_read subtile; stage 2 chunks; barrier;
// lgkmcnt(0); setprio; 16 MFMA; setprio; barrier}. Staging = 8 chunks/kt
// (B0..B3 then A0..A3; A-chunk c = rows {32c..+31} U {128+32c..+31} = exactly
// phase-c's A rows). Derived waits: vmcnt 3,4,5,6 at ph0..3 (never 0).
// 128-B LDS rows: XOR swizzle byte ^= ((row&7)<<4) on BOTH sides.
// XCD-resident grid mapping (R9-verified, FETCH 37MB).
// ---------------------------------------------------------------------------
__global__ __launch_bounds__(512, 2) void sim_main_kernel(
    const u16* __restrict__ xh, const u16* __restrict__ qh,
    float4* __restrict__ part)
{
    extern __shared__ __align__(16) char smem[];   // 2 * 65536 = 128 KB
    const int t = threadIdx.x, lane = t & 63, wid = t >> 6;
    const int wm = wid >> 2, wn = wid & 3;

    const int orig = blockIdx.x;
    const int xcd = orig & 7, s = orig >> 3;       // s in [0,128)
    const int rb = s >> 2;                          // 0..31
    const int cb = xcd * 4 + (s & 3);               // 0..31
    const int row0 = rb * BM, col0 = cb * BN;

    // ---- staging source pointers (per-lane, pre-swizzled) ----
    // thread t writes chunk-linear byte t*16; logical byte = phys ^ ((row&7)<<4)
    const int hh = t >> 8;                 // A half (0: rows 32c.., 1: 128+32c..)
    const int rr = (t >> 3) & 31;          // A row-in-32
    const int rB = t >> 3;                 // B row-in-64
    const unsigned blog = (((unsigned)t & 7u) * 16u) ^ ((((unsigned)t >> 3) & 7u) << 4);
    const u16* sA = xh + (size_t)(row0 + hh * 128 + rr) * CDIM + blog / 2;
    const u16* sB = qh + (size_t)(col0 + rB) * CDIM + blog / 2;

    // ---- frag read offsets ----
    const unsigned kx0 = ((((unsigned)lane >> 4)) * 16u) ^ ((((unsigned)lane & 7u)) << 4);
    const unsigned kx1 = (64u + (((unsigned)lane >> 4)) * 16u) ^ ((((unsigned)lane & 7u)) << 4);
    const unsigned abase = (unsigned)wm * 4096u + (unsigned)(lane & 15) * 128u;
    const unsigned bbase = 32768u + (unsigned)wn * 8192u + (unsigned)(lane & 15) * 128u;

    f32x4 acc[8][4];
#pragma unroll
    for (int i = 0; i < 8; ++i)
#pragma unroll
        for (int j = 0; j < 4; ++j) acc[i][j] = (f32x4){0.f, 0.f, 0.f, 0.f};

#define STAGE_A(BUF, KT, C) gload_lds16(sA + (size_t)(C) * (32 * CDIM) + (KT) * BK, \
        smem + (BUF) * 65536 + (C) * 8192 + wid * 1024)
#define STAGE_B(BUF, KT, W) gload_lds16(sB + (size_t)(W) * (64 * CDIM) + (KT) * BK, \
        smem + (BUF) * 65536 + 32768 + (W) * 8192 + wid * 1024)

#define READ_A(P)                                                              \
    afr[0][0] = *(const bf16x8*)(buf + abase + (P) * 8192u + kx0);             \
    afr[0][1] = *(const bf16x8*)(buf + abase + (P) * 8192u + kx1);             \
    afr[1][0] = *(const bf16x8*)(buf + abase + (P) * 8192u + 2048u + kx0);     \
    afr[1][1] = *(const bf16x8*)(buf + abase + (P) * 8192u + 2048u + kx1);

#define PHASE_MFMA(MF0)                                                        \
    __builtin_amdgcn_s_setprio(1);                                             \
    _Pragma("unroll")                                                          \
    for (int ks = 0; ks < 2; ++ks)                                             \
        _Pragma("unroll")                                                      \
        for (int m = 0; m < 2; ++m)                                            \
            _Pragma("unroll")                                                  \
            for (int nf = 0; nf < 4; ++nf)                                     \
                acc[(MF0) + m][nf] = __builtin_amdgcn_mfma_f32_16x16x32_bf16(  \
                    afr[m][ks], bfr[nf][ks], acc[(MF0) + m][nf], 0, 0, 0);     \
    __builtin_amdgcn_s_setprio(0);

#define BAR() asm volatile("" ::: "memory"); __builtin_amdgcn_s_barrier(); asm volatile("" ::: "memory")

    // ---- prologue: stage kt0 fully (issue order B0..B3, A0..A3), drain ----
    STAGE_B(0, 0, 0); STAGE_B(0, 0, 1); STAGE_B(0, 0, 2); STAGE_B(0, 0, 3);
    STAGE_A(0, 0, 0); STAGE_A(0, 0, 1); STAGE_A(0, 0, 2); STAGE_A(0, 0, 3);
    asm volatile("s_waitcnt vmcnt(0)" ::: "memory");
    __builtin_amdgcn_s_barrier();
    asm volatile("" ::: "memory");

    for (int kt = 0; kt < NT; ++kt) {
        const char* buf = smem + (unsigned)(kt & 1) * 65536u;
        const int nb = (kt + 1) & 1;
        const bool pf = (kt + 1 < NT);
        bf16x8 bfr[4][2], afr[2][2];

        // ---------- phase 0: all B + A(p0); stage B0',B1' ----------
        asm volatile("s_waitcnt vmcnt(3)" ::: "memory");
#pragma unroll
        for (int nf = 0; nf < 4; ++nf) {
            bfr[nf][0] = *(const bf16x8*)(buf + bbase + nf * 2048u + kx0);
            bfr[nf][1] = *(const bf16x8*)(buf + bbase + nf * 2048u + kx1);
        }
        READ_A(0)
        if (pf) { STAGE_B(nb, kt + 1, 0); STAGE_B(nb, kt + 1, 1); }
        BAR();
        asm volatile("s_waitcnt lgkmcnt(0)" ::: "memory");
        PHASE_MFMA(0)
        BAR();

        // ---------- phase 1: A(p1); stage B2',B3' ----------
        asm volatile("s_waitcnt vmcnt(4)" ::: "memory");
        READ_A(1)
        if (pf) { STAGE_B(nb, kt + 1, 2); STAGE_B(nb, kt + 1, 3); }
        BAR();
        asm volatile("s_waitcnt lgkmcnt(0)" ::: "memory");
        PHASE_MFMA(2)
        BAR();

        // ---------- phase 2: A(p2); stage A0',A1' ----------
        asm volatile("s_waitcnt vmcnt(5)" ::: "memory");
        READ_A(2)
        if (pf) { STAGE_A(nb, kt + 1, 0); STAGE_A(nb, kt + 1, 1); }
        BAR();
        asm volatile("s_waitcnt lgkmcnt(0)" ::: "memory");
        PHASE_MFMA(4)
        BAR();

        // ---------- phase 3: A(p3); stage A2',A3' ----------
        asm volatile("s_waitcnt vmcnt(6)" ::: "memory");
        READ_A(3)
        if (pf) { STAGE_A(nb, kt + 1, 2); STAGE_A(nb, kt + 1, 3); }
        BAR();
        asm volatile("s_waitcnt lgkmcnt(0)" ::: "memory");
        PHASE_MFMA(6)
        BAR();
    }
#undef STAGE_A
#undef STAGE_B
#undef READ_A
#undef PHASE_MFMA
#undef BAR

    // ---- epilogue: per-row (max, sum-exp, argmax) + in-tile diag ----
    // C/D layout: row = (lane>>4)*4 + reg, col = lane&15 (verified R1-R10).
    __syncthreads();
    float* sm = (float*)smem;              // [256][4] row max (logit units)
    float* sl = sm + 1024;                 // [256][4] sum exp
    int*   si = (int*)(sl + 1024);         // [256][4] argmax col
    float* sd = (float*)(si + 1024);       // [256] diag (logit units)
    const int g = lane >> 4;
#pragma unroll
    for (int mf = 0; mf < 8; ++mf) {
#pragma unroll
        for (int r = 0; r < 4; ++r) {
            const int row_loc  = wm * 128 + mf * 16 + g * 4 + r;
            const int row_glob = row0 + row_loc;
            const int ci = col0 + wn * 64 + (lane & 15);
            float vmax = acc[mf][0][r];
            int cbest = ci;
#pragma unroll
            for (int nf = 1; nf < 4; ++nf) {
                float v = acc[mf][nf][r];
                if (v > vmax) { vmax = v; cbest = ci + nf * 16; }
                if (ci + nf * 16 == row_glob) sd[row_loc] = v * TEMP_INV;
            }
            if (ci == row_glob) sd[row_loc] = acc[mf][0][r] * TEMP_INV;
#pragma unroll
            for (int m = 1; m < 16; m <<= 1) {
                float ov = __shfl_xor(vmax, m);
                int   oi = __shfl_xor(cbest, m);
                if (ov > vmax || (ov == vmax && oi < cbest)) { vmax = ov; cbest = oi; }
            }
            float ssum = 0.f;
#pragma unroll
            for (int nf = 0; nf < 4; ++nf)
                ssum += __expf((acc[mf][nf][r] - vmax) * TEMP_INV);
#pragma unroll
            for (int m = 1; m < 16; m <<= 1) ssum += __shfl_xor(ssum, m);
            if ((lane & 15) == 0) {
                sm[row_loc * 4 + wn] = vmax * TEMP_INV;
                sl[row_loc * 4 + wn] = ssum;
                si[row_loc * 4 + wn] = cbest;
            }
        }
    }
    __syncthreads();
    if (t < 256) {
        float M = sm[t * 4];
#pragma unroll
        for (int w = 1; w < 4; ++w) M = fmaxf(M, sm[t * 4 + w]);
        float L = 0.f;
#pragma unroll
        for (int w = 0; w < 4; ++w) L += sl[t * 4 + w] * __expf(sm[t * 4 + w] - M);
        float bv = -1e30f; int bi = 0;
#pragma unroll
        for (int w = 0; w < 4; ++w) {      // ascending wn: first-index tiebreak
            float v = sm[t * 4 + w];
            if (v > bv) { bv = v; bi = si[t * 4 + w]; }
        }
        part[(size_t)(row0 + t) * NCB + cb] =
            make_float4(M, L, __int_as_float(bi), sd[t]);
    }
}

// ---------------------------------------------------------------------------
// Kernel 3: per-row merge of 32 chunk partials -> loss_i / correct_i.
// One wave per row; lanes>=32 hold duplicates (zeroed for the sum).
// Diag comes from chunk (i>>8).
// ---------------------------------------------------------------------------
__global__ __launch_bounds__(256) void merge_kernel(
    const float4* __restrict__ part,
    float* __restrict__ loss_arr, float* __restrict__ corr_arr)
{
    int i    = blockIdx.x * 4 + (threadIdx.x >> 6);
    int lane = threadIdx.x & 63;
    float4 v = part[(size_t)i * NCB + (lane & 31)];

    float M = v.x;
#pragma unroll
    for (int off = 32; off; off >>= 1) M = fmaxf(M, __shfl_xor(M, off));
    float L = (lane < 32) ? v.y * __expf(v.x - M) : 0.f;
#pragma unroll
    for (int off = 32; off; off >>= 1) L += __shfl_xor(L, off);
    float bm = v.x; int bi = __float_as_int(v.z);
#pragma unroll
    for (int off = 1; off < 32; off <<= 1) {   // first-index tiebreak
        float ov = __shfl_xor(bm, off);
        int   oi = __shfl_xor(bi, off);
        if (ov > bm || (ov == bm && oi < bi)) { bm = ov; bi = oi; }
    }
    float dg = __shfl(v.w, i >> 8);
    if (lane == 0) {
        loss_arr[i] = (M + logf(L)) - dg;
        corr_arr[i] = (bi == i) ? 1.0f : 0.0f;
    }
}

// ---------------------------------------------------------------------------
// Kernel 4: deterministic single-block mean reduction -> d_out[0..1]
// ---------------------------------------------------------------------------
__global__ __launch_bounds__(256) void finalize_kernel(
    const float* __restrict__ loss_arr, const float* __restrict__ corr_arr,
    float* __restrict__ out, int n)
{
    float a = 0.f, b = 0.f;
    for (int i = threadIdx.x; i < n; i += 256) { a += loss_arr[i]; b += corr_arr[i]; }
#pragma unroll
    for (int off = 32; off; off >>= 1) { a += __shfl_xor(a, off); b += __shfl_xor(b, off); }
    __shared__ float sa[4], sb[4];
    int wid = threadIdx.x >> 6, lane = threadIdx.x & 63;
    if (lane == 0) { sa[wid] = a; sb[wid] = b; }
    __syncthreads();
    if (threadIdx.x == 0) {
        out[0] = (sa[0] + sa[1] + sa[2] + sa[3]) / n;
        out[1] = (sb[0] + sb[1] + sb[2] + sb[3]) / n;
    }
}

extern "C" void kernel_launch(void* const* d_in, const int* in_sizes, int n_in,
                              void* d_out, int out_size, void* d_ws, size_t ws_size,
                              hipStream_t stream)
{
    const float* x = (const float*)d_in[0];
    const float* q = (const float*)d_in[1];
    const int n = in_sizes[0] / CDIM;   // 8192

    char* ws = (char*)d_ws;
    size_t sz_bf = (size_t)n * CDIM * sizeof(u16);   // 8 MB each
    u16* xh = (u16*)(ws);
    u16* qh = (u16*)(ws + sz_bf);
    char* p = ws + 2 * sz_bf;
    float4* part = (float4*)p; p += (size_t)n * NCB * sizeof(float4);  // 4 MB
    float* loss_arr = (float*)p; p += (size_t)n * 4;
    float* corr_arr = (float*)p;

    norm_split_kernel<<<(2 * n) / 4, 256, 0, stream>>>(x, q, xh, qh, n);

    sim_main_kernel<<<(n / BM) * (n / BN), 512, 131072, stream>>>(xh, qh, part);

    merge_kernel<<<n / 4, 256, 0, stream>>>(part, loss_arr, corr_arr);

    finalize_kernel<<<1, 256, 0, stream>>>(loss_arr, corr_arr, (float*)d_out, n);
}